// Round 8
// baseline (1144.759 us; speedup 1.0000x reference)
//
#include <hip/hip_runtime.h>
#include <hip/hip_bf16.h>

#define Bn 4096
#define Tn 8
#define Hn 512

typedef __attribute__((ext_vector_type(8))) _Float16 half8v;
typedef __attribute__((ext_vector_type(4))) float f32x4;

__device__ __forceinline__ float sigm(float x) { return 0.5f * tanhf(0.5f * x) + 0.5f; }

__device__ __forceinline__ short f2h(float x) {
    _Float16 h = (_Float16)x;
    return *reinterpret_cast<short*>(&h);
}
__device__ __forceinline__ float h2f(short s) {
    _Float16 h = *reinterpret_cast<_Float16*>(&s);
    return (float)h;
}
// x ~= hi + lo*2^-12 ; lo pre-scaled by 2^12 so it stays fp16-normal
__device__ __forceinline__ void split2(float x, short& hi, short& lo) {
    hi = f2h(x);
    lo = f2h((x - h2f(hi)) * 4096.0f);
}

#define GLOAD16(g, l) __builtin_amdgcn_global_load_lds( \
    (const __attribute__((address_space(1))) unsigned int*)(g), \
    (__attribute__((address_space(3))) unsigned int*)(l), 16, 0, 0)

// A-side fragment layout (fp16 pair arrays): flat = ((M16*kts + kt)*64 + lane)*8 + e
// where lane = lk*16+lm holds row M16*16+lm, k-elems kt*32 + lk*8 + e.

// ---------------- setup kernels ----------------

// Wcat rows remapped: j' = (h&15) | (gate<<4) | ((h>>4)<<6), source row = gate*512 + h.
__global__ __launch_bounds__(256) void k_prep(const float* __restrict__ Wih,
                                              const float* __restrict__ Whh,
                                              const float* __restrict__ bih,
                                              const float* __restrict__ bhh,
                                              short* __restrict__ WcatHi,
                                              short* __restrict__ WcatLo,
                                              float* __restrict__ bcat) {
    int tid = blockIdx.x * 256 + threadIdx.x;   // over 2048*1024
    int jp = tid >> 10, k = tid & 1023;
    int g = (jp >> 4) & 3;
    int h = (jp & 15) + ((jp >> 6) << 4);
    int j = g * 512 + h;                        // source row in [Wih|Whh]
    float v = (k < 512) ? Wih[j * 512 + k] : Whh[j * 512 + (k - 512)];
    short hi, lo; split2(v, hi, lo);
    WcatHi[tid] = hi; WcatLo[tid] = lo;
    if (k == 0) bcat[jp] = bih[j] + bhh[j];
}

// row-major split (B-side weights W1, W2)
__global__ __launch_bounds__(256) void k_split4(const float* __restrict__ x,
                                                short* __restrict__ hi,
                                                short* __restrict__ lo, int n4) {
    int i = blockIdx.x * 256 + threadIdx.x;
    if (i >= n4) return;
    float4 v = ((const float4*)x)[i];
    short h0, l0, h1, l1, h2, l2, h3, l3;
    split2(v.x, h0, l0); split2(v.y, h1, l1);
    split2(v.z, h2, l2); split2(v.w, h3, l3);
    ((short4*)hi)[i] = make_short4(h0, h1, h2, h3);
    ((short4*)lo)[i] = make_short4(l0, l1, l2, l3);
}

// enc [32768,512] fp32 -> fragment-layout fp16 pair (kts=16)
__global__ __launch_bounds__(256) void k_encfrag(const float* __restrict__ enc,
                                                 short* __restrict__ hi,
                                                 short* __restrict__ lo) {
    int idx = blockIdx.x * 256 + threadIdx.x;   // over 32768*64 chunks
    int row = idx >> 6, c = idx & 63;
    const float4* p = (const float4*)(enc + (size_t)row * 512 + c * 8);
    float4 u0 = p[0], u1 = p[1];
    short h[8], l[8];
    split2(u0.x, h[0], l[0]); split2(u0.y, h[1], l[1]);
    split2(u0.z, h[2], l[2]); split2(u0.w, h[3], l[3]);
    split2(u1.x, h[4], l[4]); split2(u1.y, h[5], l[5]);
    split2(u1.z, h[6], l[6]); split2(u1.w, h[7], l[7]);
    size_t base = (((size_t)(row >> 4) * 16 + (c >> 2)) * 512) + (c & 3) * 128 + (row & 15) * 8;
    *(short4*)(hi + base) = make_short4(h[0], h[1], h[2], h[3]);
    *(short4*)(hi + base + 4) = make_short4(h[4], h[5], h[6], h[7]);
    *(short4*)(lo + base) = make_short4(l[0], l[1], l[2], l[3]);
    *(short4*)(lo + base + 4) = make_short4(l[4], l[5], l[6], l[7]);
}

// inp0 into Xfrag (k=h), zero h-part (k=512+h), zero C, zero mask
__global__ __launch_bounds__(256) void k_init(const float* __restrict__ enc,
                                              const float* __restrict__ cw,
                                              const float* __restrict__ cb,
                                              short* __restrict__ Xhi,
                                              short* __restrict__ Xlo,
                                              float* __restrict__ C,
                                              int* __restrict__ mask) {
    int idx = blockIdx.x * 256 + threadIdx.x;   // over 4096*64 chunks
    int b = idx >> 6, c = idx & 63;
    int h0 = c * 8;
    float s[8];
#pragma unroll
    for (int e = 0; e < 8; ++e) s[e] = cb[0];
#pragma unroll
    for (int t = 0; t < Tn; ++t) {
        const float4* p = (const float4*)(enc + ((size_t)b << 12) + t * Hn + h0);
        float4 u0 = p[0], u1 = p[1];
        float w = cw[t];
        s[0] = fmaf(u0.x, w, s[0]); s[1] = fmaf(u0.y, w, s[1]);
        s[2] = fmaf(u0.z, w, s[2]); s[3] = fmaf(u0.w, w, s[3]);
        s[4] = fmaf(u1.x, w, s[4]); s[5] = fmaf(u1.y, w, s[5]);
        s[6] = fmaf(u1.z, w, s[6]); s[7] = fmaf(u1.w, w, s[7]);
    }
    short h[8], l[8];
#pragma unroll
    for (int e = 0; e < 8; ++e) split2(s[e], h[e], l[e]);
    size_t bi = ((size_t)(b >> 4) * 32 + (c >> 2)) * 512 + (c & 3) * 128 + (b & 15) * 8;
    size_t bz = ((size_t)(b >> 4) * 32 + 16 + (c >> 2)) * 512 + (c & 3) * 128 + (b & 15) * 8;
    *(short4*)(Xhi + bi) = make_short4(h[0], h[1], h[2], h[3]);
    *(short4*)(Xhi + bi + 4) = make_short4(h[4], h[5], h[6], h[7]);
    *(short4*)(Xlo + bi) = make_short4(l[0], l[1], l[2], l[3]);
    *(short4*)(Xlo + bi + 4) = make_short4(l[4], l[5], l[6], l[7]);
    short4 z = make_short4(0, 0, 0, 0);
    *(short4*)(Xhi + bz) = z; *(short4*)(Xhi + bz + 4) = z;
    *(short4*)(Xlo + bz) = z; *(short4*)(Xlo + bz + 4) = z;
    float4 zf = make_float4(0.f, 0.f, 0.f, 0.f);
    *(float4*)(C + (size_t)b * 512 + h0) = zf;
    *(float4*)(C + (size_t)b * 512 + h0 + 4) = zf;
    if (c == 0) mask[b] = 0;
}

// ---------------- split-fp16 MFMA GEMM: A from global (fragment layout), B via LDS ----
// C[m,n] = sum_k (Ahi + Alo*2^-12)[m,k] * (Whi + Wlo*2^-12)[n,k] + bias[n]
// BM=128, BN=32*NW, BK=32; 4 waves as 2x2. B double-buffered in LDS; A-fragments
// prefetched one K-step ahead into registers (unroll-2). One barrier per K-step.
template <int NW, bool FUSE, int SWZ>
__global__ __launch_bounds__(256) void gemm_t(
    const short* __restrict__ Ahi, const short* __restrict__ Alo,
    int kts, int kbase,
    const short* __restrict__ Whi, const short* __restrict__ Wlo,
    const float* __restrict__ bias, float* __restrict__ out,
    float* __restrict__ Cst, short* __restrict__ Xh, short* __restrict__ Xl,
    int N, int K) {
    constexpr int BN = 32 * NW;
    constexpr int BUFSH = 2 * BN * 32;             // shorts per buffer (Bhi+Blo)
    __shared__ short sm[2 * BUFSH];

    int bx = blockIdx.x, by = blockIdx.y;
    if constexpr (SWZ == 1) {
        int w = bx + (by << 4), c = w & 7, k = w >> 3;
        by = ((c >> 1) << 3) | (k >> 3);
        bx = ((c & 1) << 3) | (k & 7);
    } else if constexpr (SWZ == 2) {
        int w = bx + (by << 2), c = w & 7, k = w >> 3;
        by = (c << 5) | (k >> 2);
        bx = k & 3;
    } else if constexpr (SWZ == 3) {
        int w = bx + (by << 3), c = w & 7, k = w >> 3;
        by = ((c >> 1) << 3) | (k >> 2);
        bx = ((c & 1) << 2) | (k & 3);
    }

    const int tid = threadIdx.x;
    const int lane = tid & 63;
    const int wv = tid >> 6;
    const int wm = wv >> 1, wn = wv & 1;
    const int lm = lane & 15, lk = lane >> 4;
    const int m0 = by * 128, n0 = bx * BN;
    const int m16b = (m0 >> 4) + wm * 4;

    const int sq = lane & 3;
    const int srow = wv * 16 + (lane >> 2);

    f32x4 acc[4][NW] = {};
    f32x4 acc2[4][NW] = {};

    float bb[NW];
#pragma unroll
    for (int j = 0; j < NW; ++j) bb[j] = bias[n0 + wn * (16 * NW) + j * 16 + lm];

    // stage B tile (kt) into buffer buf: pre-swizzled source, linear LDS dest
    auto STAGE_B = [&](int buf, int kt) {
        short* base = sm + buf * BUFSH;
        int k0 = kt << 5;
#pragma unroll
        for (int half = 0; half < BN / 64; ++half) {
            int r = half * 64 + srow;
            int qg = sq ^ ((r >> 1) & 3);
            size_t boff = (size_t)(n0 + r) * K + k0 + qg * 8;
            int lb = half * 2048 + wv * 512;
            GLOAD16(Whi + boff, base + lb);
            GLOAD16(Wlo + boff, base + BN * 32 + lb);
        }
    };
    // load A fragments (kt) from global, fragment layout
    auto LDA = [&](half8v (&ah)[4], half8v (&al)[4], int kt) {
#pragma unroll
        for (int i = 0; i < 4; ++i) {
            size_t off = (((size_t)(m16b + i) * kts + kbase + kt) * 64 + lane) * 8;
            ah[i] = *(const half8v*)(Ahi + off);
            al[i] = *(const half8v*)(Alo + off);
        }
    };
    auto COMP = [&](half8v (&ah)[4], half8v (&al)[4], int buf) {
        short* base = sm + buf * BUFSH;
        half8v bhi[NW], blo[NW];
#pragma unroll
        for (int j = 0; j < NW; ++j) {
            int rb = wn * (16 * NW) + j * 16 + lm;
            int offb = rb * 32 + (lk ^ ((rb >> 1) & 3)) * 8;
            bhi[j] = *(const half8v*)&base[offb];
            blo[j] = *(const half8v*)&base[BN * 32 + offb];
        }
#pragma unroll
        for (int i = 0; i < 4; ++i)
#pragma unroll
            for (int j = 0; j < NW; ++j) {
                acc[i][j]  = __builtin_amdgcn_mfma_f32_16x16x32_f16(ah[i], bhi[j], acc[i][j], 0, 0, 0);
                acc2[i][j] = __builtin_amdgcn_mfma_f32_16x16x32_f16(ah[i], blo[j], acc2[i][j], 0, 0, 0);
                acc2[i][j] = __builtin_amdgcn_mfma_f32_16x16x32_f16(al[i], bhi[j], acc2[i][j], 0, 0, 0);
            }
    };

    half8v A0h[4], A0l[4], A1h[4], A1l[4];
    const int nkt = K >> 5;                       // even for all our shapes
    STAGE_B(0, 0);
    LDA(A0h, A0l, 0);
    for (int kt = 0; kt < nkt; kt += 2) {
        __syncthreads();                          // buf0 staged; prior buf1 reads done
        STAGE_B(1, kt + 1);
        LDA(A1h, A1l, kt + 1);
        COMP(A0h, A0l, 0);
        __syncthreads();                          // buf1 staged; buf0 reads done
        if (kt + 2 < nkt) { STAGE_B(0, kt + 2); LDA(A0h, A0l, kt + 2); }
        COMP(A1h, A1l, 1);
    }

    const float ls = 1.0f / 4096.0f;

    if constexpr (FUSE) {
        // col = n0 + wn*64 + gate*16 + lm  ->  gate = j, h = lm + 16*(n0/64 + wn)
        const int h = lm + 16 * ((n0 >> 6) + wn);
        const size_t hoff = ((size_t)(16 + (h >> 5))) * 512 + ((h >> 3) & 3) * 128 + (h & 7);
#pragma unroll
        for (int i = 0; i < 4; ++i) {
            size_t mbase = (size_t)(m16b + i) * 32 * 512 + hoff;
#pragma unroll
            for (int r = 0; r < 4; ++r) {
                int brow = m0 + wm * 64 + i * 16 + lk * 4 + r;
                float gi = acc[i][0][r] + ls * acc2[i][0][r] + bb[0];
                float gf = acc[i][1][r] + ls * acc2[i][1][r] + bb[1];
                float gg = acc[i][2][r] + ls * acc2[i][2][r] + bb[2];
                float go = acc[i][3][r] + ls * acc2[i][3][r] + bb[3];
                size_t ch = ((size_t)brow << 9) + h;
                float c = sigm(gf) * Cst[ch] + sigm(gi) * tanhf(gg);
                float hn = sigm(go) * tanhf(c);
                Cst[ch] = c;
                short shi, slo; split2(hn, shi, slo);
                size_t xb = mbase + (lk * 4 + r) * 8;
                Xh[xb] = shi; Xl[xb] = slo;
            }
        }
    } else {
        __syncthreads();                          // all B reads complete (LDS reuse)
        // LDS-transpose epilogue -> coalesced float4 stores
        constexpr int SW = 16 * NW + 4;
        float* tile = reinterpret_cast<float*>(sm) + wv * 16 * SW;
        constexpr int LPR = 4 * NW;
        const int rl = lane / LPR, cc = lane % LPR;
#pragma unroll
        for (int i = 0; i < 4; ++i) {
#pragma unroll
            for (int j = 0; j < NW; ++j)
#pragma unroll
                for (int r = 0; r < 4; ++r)
                    tile[(lk * 4 + r) * SW + j * 16 + lm] = acc[i][j][r] + ls * acc2[i][j][r] + bb[j];
            constexpr int RPS = 64 / LPR;
#pragma unroll
            for (int s = 0; s < 16 / RPS; ++s) {
                int row = s * RPS + rl;
                float4 v = *(float4*)&tile[row * SW + cc * 4];
                *(float4*)(out + (size_t)(m0 + wm * 64 + i * 16 + row) * N +
                           n0 + wn * (16 * NW) + cc * 4) = v;
            }
        }
    }
}

// ---------------- attention + argmax + mask + gather into X_next (frag layout) --------
__global__ __launch_bounds__(256) void k_attn(const float* __restrict__ W1E,
                                              const float* __restrict__ W2h,
                                              const float* __restrict__ vw,
                                              const float* __restrict__ vbp,
                                              const float* __restrict__ inps,
                                              short* __restrict__ Xhi,
                                              short* __restrict__ Xlo,
                                              int* __restrict__ mask,
                                              float* __restrict__ probs,
                                              float* __restrict__ ptrs,
                                              int step) {
    const int b = blockIdx.x;
    const int tid = threadIdx.x;
    const int lane = tid & 63;
    const int wv = tid >> 6;
    __shared__ float sU[Tn];
    __shared__ int sptr;

    const float4* w2p = (const float4*)(W2h + (size_t)b * Hn + lane * 8);
    float4 w2a = w2p[0], w2b = w2p[1];
    const float4* vp = (const float4*)(vw + lane * 8);
    float4 va = vp[0], vb4 = vp[1];
    float vbias = vbp[0];

#pragma unroll
    for (int q = 0; q < 2; ++q) {
        int t = wv * 2 + q;
        const float4* w1 = (const float4*)(W1E + ((size_t)b << 12) + t * Hn + lane * 8);
        float4 u0 = w1[0], u1 = w1[1];
        float p = va.x * tanhf(u0.x + w2a.x) + va.y * tanhf(u0.y + w2a.y)
                + va.z * tanhf(u0.z + w2a.z) + va.w * tanhf(u0.w + w2a.w)
                + vb4.x * tanhf(u1.x + w2b.x) + vb4.y * tanhf(u1.y + w2b.y)
                + vb4.z * tanhf(u1.z + w2b.z) + vb4.w * tanhf(u1.w + w2b.w);
#pragma unroll
        for (int off = 32; off; off >>= 1) p += __shfl_down(p, off, 64);
        if (lane == 0) sU[t] = p + vbias;
    }
    __syncthreads();

    if (tid == 0) {
        int mk = mask[b];
        float best = -1e30f;
        int ptr = 0;
#pragma unroll
        for (int t = 0; t < Tn; ++t) {
            probs[(size_t)b * 64 + step * 8 + t] = sU[t];
            if (!((mk >> t) & 1) && sU[t] > best) { best = sU[t]; ptr = t; }
        }
        mask[b] = mk | (1 << ptr);
        ptrs[(size_t)b * 8 + step] = (float)ptr;
        sptr = ptr;
    }
    __syncthreads();
    if (tid < 64) {
        int c = tid;
        const float4* src = (const float4*)(inps + ((size_t)b << 12) + (size_t)sptr * Hn + c * 8);
        float4 u0 = src[0], u1 = src[1];
        short h[8], l[8];
        split2(u0.x, h[0], l[0]); split2(u0.y, h[1], l[1]);
        split2(u0.z, h[2], l[2]); split2(u0.w, h[3], l[3]);
        split2(u1.x, h[4], l[4]); split2(u1.y, h[5], l[5]);
        split2(u1.z, h[6], l[6]); split2(u1.w, h[7], l[7]);
        size_t base = ((size_t)(b >> 4) * 32 + (c >> 2)) * 512 + (c & 3) * 128 + (b & 15) * 8;
        *(short4*)(Xhi + base) = make_short4(h[0], h[1], h[2], h[3]);
        *(short4*)(Xhi + base + 4) = make_short4(h[4], h[5], h[6], h[7]);
        *(short4*)(Xlo + base) = make_short4(l[0], l[1], l[2], l[3]);
        *(short4*)(Xlo + base + 4) = make_short4(l[4], l[5], l[6], l[7]);
    }
}

// ---------------- launch ----------------
extern "C" void kernel_launch(void* const* d_in, const int* in_sizes, int n_in,
                              void* d_out, int out_size, void* d_ws, size_t ws_size,
                              hipStream_t stream) {
    const float* inps  = (const float*)d_in[0];
    const float* enc   = (const float*)d_in[1];
    const float* convw = (const float*)d_in[2];
    const float* convb = (const float*)d_in[3];
    const float* Wih   = (const float*)d_in[4];
    const float* Whh   = (const float*)d_in[5];
    const float* bih   = (const float*)d_in[6];
    const float* bhh   = (const float*)d_in[7];
    const float* W1    = (const float*)d_in[8];
    const float* b1    = (const float*)d_in[9];
    const float* W2    = (const float*)d_in[10];
    const float* b2    = (const float*)d_in[11];
    const float* vw    = (const float*)d_in[12];
    const float* vb    = (const float*)d_in[13];

    float* out   = (float*)d_out;
    float* probs = out;                       // [B, 8, 8]
    float* ptrs  = out + (size_t)Bn * 64;     // [B, 8] as float

    char* wsb = (char*)d_ws;
    float* W1E    = (float*)wsb;                          // [0,64MB) fp32 [B*T,512]
    short* encHi  = (short*)(wsb + (64ull << 20));        // frag, dead after W1E gemm
    short* encLo  = (short*)(wsb + (96ull << 20));        // frag, dead after W1E gemm
    short* Xhi1   = (short*)(wsb + (64ull << 20));        // 8MB fp16 frag [B,1024]
    short* Xlo1   = (short*)(wsb + (72ull << 20));        // 8MB
    float* W2h    = (float*)(wsb + (96ull << 20));        // 8MB fp32 [B,512]
    float* C      = (float*)(wsb + (104ull << 20));       // 8MB fp32 [B,512]
    short* Xhi0   = (short*)(wsb + (112ull << 20));       // 8MB frag
    short* Xlo0   = (short*)(wsb + (120ull << 20));       // 8MB frag
    short* WcatHi = (short*)(wsb + (128ull << 20));       // 4MB [2048,1024]
    short* WcatLo = (short*)(wsb + (132ull << 20));       // 4MB
    short* W1hi   = (short*)(wsb + (136ull << 20));
    short* W1lo   = (short*)(wsb + (136ull << 20) + (512u << 10));
    short* W2hi   = (short*)(wsb + (137ull << 20));
    short* W2lo   = (short*)(wsb + (137ull << 20) + (512u << 10));
    float* bcat   = (float*)(wsb + (138ull << 20));
    int*   mask   = (int*)(wsb + (138ull << 20) + (16u << 10));

    k_prep<<<(2048 * 1024) / 256, 256, 0, stream>>>(Wih, Whh, bih, bhh, WcatHi, WcatLo, bcat);
    k_encfrag<<<(Bn * Tn * 64) / 256, 256, 0, stream>>>(enc, encHi, encLo);
    k_split4<<<(Hn * Hn / 4) / 256, 256, 0, stream>>>(W1, W1hi, W1lo, Hn * Hn / 4);
    k_split4<<<(Hn * Hn / 4) / 256, 256, 0, stream>>>(W2, W2hi, W2lo, Hn * Hn / 4);

    // W1E = enc @ W1^T + b1   [B*T, 512], K=512 (enc frag kts=16)
    gemm_t<4, false, 2><<<dim3(Hn / 128, (Bn * Tn) / 128), 256, 0, stream>>>(
        encHi, encLo, 16, 0, W1hi, W1lo, b1, W1E, nullptr, nullptr, nullptr, Hn, Hn);

    k_init<<<(Bn * 64) / 256, 256, 0, stream>>>(enc, convw, convb, Xhi0, Xlo0, C, mask);

    for (int step = 0; step < Tn; ++step) {
        short* Xh_cur = (step & 1) ? Xhi1 : Xhi0;
        short* Xl_cur = (step & 1) ? Xlo1 : Xlo0;
        short* Xh_nxt = (step & 1) ? Xhi0 : Xhi1;
        short* Xl_nxt = (step & 1) ? Xlo0 : Xlo1;

        // gates GEMM + fused LSTM cell: reads X_cur (frag), writes h into X_next (frag)
        gemm_t<4, true, 1><<<dim3(2048 / 128, Bn / 128), 256, 0, stream>>>(
            Xh_cur, Xl_cur, 32, 0, WcatHi, WcatLo, bcat, nullptr, C, Xh_nxt, Xl_nxt, 2048, 1024);
        // W2h = h @ W2^T + b2   [4096,512], K=512  (h = X_next frag, kbase=16)
        gemm_t<2, false, 3><<<dim3(Hn / 64, Bn / 128), 256, 0, stream>>>(
            Xh_nxt, Xl_nxt, 32, 16, W2hi, W2lo, b2, W2h, nullptr, nullptr, nullptr, Hn, Hn);
        // attention, argmax, mask, gather next input into X_next (frag, kbase=0)
        k_attn<<<Bn, 256, 0, stream>>>(W1E, W2h, vw, vb, inps, Xh_nxt, Xl_nxt, mask, probs, ptrs, step);
    }
}

// Round 9
// 934.389 us; speedup vs baseline: 1.2251x; 1.2251x over previous
//
#include <hip/hip_runtime.h>
#include <hip/hip_bf16.h>

#define Bn 4096
#define Tn 8
#define Hn 512

typedef __attribute__((ext_vector_type(8))) _Float16 half8v;
typedef __attribute__((ext_vector_type(4))) float f32x4;

__device__ __forceinline__ float sigm(float x) { return 0.5f * tanhf(0.5f * x) + 0.5f; }

__device__ __forceinline__ short f2h(float x) {
    _Float16 h = (_Float16)x;
    return *reinterpret_cast<short*>(&h);
}
__device__ __forceinline__ float h2f(short s) {
    _Float16 h = *reinterpret_cast<_Float16*>(&s);
    return (float)h;
}
// x ~= hi + lo*2^-12 ; lo pre-scaled by 2^12 so it stays fp16-normal
__device__ __forceinline__ void split2(float x, short& hi, short& lo) {
    hi = f2h(x);
    lo = f2h((x - h2f(hi)) * 4096.0f);
}

#define GLOAD16(g, l) __builtin_amdgcn_global_load_lds( \
    (const __attribute__((address_space(1))) unsigned int*)(g), \
    (__attribute__((address_space(3))) unsigned int*)(l), 16, 0, 0)

// ---------------- setup kernels ----------------

// Wcat rows remapped: j' = (h&15) | (gate<<4) | ((h>>4)<<6), source row = gate*512 + h.
__global__ __launch_bounds__(256) void k_prep(const float* __restrict__ Wih,
                                              const float* __restrict__ Whh,
                                              const float* __restrict__ bih,
                                              const float* __restrict__ bhh,
                                              short* __restrict__ WcatHi,
                                              short* __restrict__ WcatLo,
                                              float* __restrict__ bcat) {
    int tid = blockIdx.x * 256 + threadIdx.x;   // over 2048*1024
    int jp = tid >> 10, k = tid & 1023;
    int g = (jp >> 4) & 3;
    int h = (jp & 15) + ((jp >> 6) << 4);
    int j = g * 512 + h;                        // source row in [Wih|Whh]
    float v = (k < 512) ? Wih[j * 512 + k] : Whh[j * 512 + (k - 512)];
    short hi, lo; split2(v, hi, lo);
    WcatHi[tid] = hi; WcatLo[tid] = lo;
    if (k == 0) bcat[jp] = bih[j] + bhh[j];
}

__global__ __launch_bounds__(256) void k_split4(const float* __restrict__ x,
                                                short* __restrict__ hi,
                                                short* __restrict__ lo, int n4) {
    int i = blockIdx.x * 256 + threadIdx.x;
    if (i >= n4) return;
    float4 v = ((const float4*)x)[i];
    short h0, l0, h1, l1, h2, l2, h3, l3;
    split2(v.x, h0, l0); split2(v.y, h1, l1);
    split2(v.z, h2, l2); split2(v.w, h3, l3);
    ((short4*)hi)[i] = make_short4(h0, h1, h2, h3);
    ((short4*)lo)[i] = make_short4(l0, l1, l2, l3);
}

// inp0 = sum_t enc[b,t,h]*cw[t] + cb ; zero h-part of X0, zero C, zero mask
__global__ __launch_bounds__(256) void k_init(const float* __restrict__ enc,
                                              const float* __restrict__ cw,
                                              const float* __restrict__ cb,
                                              short* __restrict__ Xhi,
                                              short* __restrict__ Xlo,
                                              float* __restrict__ C,
                                              int* __restrict__ mask) {
    int tid = blockIdx.x * 256 + threadIdx.x;   // over B*H
    int b = tid >> 9, h = tid & 511;
    float s = cb[0];
    const float* e = enc + ((size_t)b << 12) + h;
#pragma unroll
    for (int t = 0; t < Tn; ++t) s = fmaf(e[t * Hn], cw[t], s);
    short hi, lo; split2(s, hi, lo);
    size_t xb = ((size_t)b << 10) + h;
    Xhi[xb] = hi; Xlo[xb] = lo;
    Xhi[xb + 512] = 0; Xlo[xb + 512] = 0;
    C[tid] = 0.0f;
    if (h == 0) mask[b] = 0;
}

// ---------------- split-fp16 MFMA GEMM, double-buffered 2-phase (round-7) -------------
// SWZ: 2: grid(4,256) -> 32 full rows per XCD (W1E); 3: grid(8,32) -> 8x4 (W2h)
template <int NW, int SWZ>
__global__ __launch_bounds__(256) void gemm_t(
    const short* __restrict__ Ahi, const short* __restrict__ Alo, int lda,
    const short* __restrict__ Whi, const short* __restrict__ Wlo,
    const float* __restrict__ bias, float* __restrict__ out,
    int N, int K) {
    constexpr int BN = 32 * NW;
    constexpr int BUFSH = (256 + 2 * BN) * 32;     // shorts per buffer
    __shared__ short sm[2 * BUFSH];

    int bx = blockIdx.x, by = blockIdx.y;
    if constexpr (SWZ == 2) {
        int w = bx + (by << 2), c = w & 7, k = w >> 3;
        by = (c << 5) | (k >> 2);
        bx = k & 3;
    } else if constexpr (SWZ == 3) {
        int w = bx + (by << 3), c = w & 7, k = w >> 3;
        by = ((c >> 1) << 3) | (k >> 2);
        bx = ((c & 1) << 2) | (k & 3);
    }

    const int tid = threadIdx.x;
    const int lane = tid & 63;
    const int wv = tid >> 6;
    const int wm = wv >> 1, wn = wv & 1;
    const int lm = lane & 15, lk = lane >> 4;
    const int m0 = by * 128, n0 = bx * BN;

    const int sq = lane & 3;
    const int srow = wv * 16 + (lane >> 2);

    f32x4 acc[4][NW] = {};
    f32x4 acc2[4][NW] = {};

    float bb[NW];
#pragma unroll
    for (int j = 0; j < NW; ++j) bb[j] = bias[n0 + wn * (16 * NW) + j * 16 + lm];

    auto STAGE = [&](int buf, int k0) {
        short* base = sm + buf * BUFSH;
#pragma unroll
        for (int half = 0; half < 2; ++half) {
            int r = half * 64 + srow;
            int qg = sq ^ ((r >> 1) & 3);
            size_t aoff = (size_t)(m0 + r) * lda + k0 + qg * 8;
            int lb = half * 2048 + wv * 512;
            GLOAD16(Ahi + aoff, base + lb);
            GLOAD16(Alo + aoff, base + 128 * 32 + lb);
        }
#pragma unroll
        for (int half = 0; half < BN / 64; ++half) {
            int r = half * 64 + srow;
            int qg = sq ^ ((r >> 1) & 3);
            size_t boff = (size_t)(n0 + r) * K + k0 + qg * 8;
            int lb = half * 2048 + wv * 512;
            GLOAD16(Whi + boff, base + 256 * 32 + lb);
            GLOAD16(Wlo + boff, base + (256 + BN) * 32 + lb);
        }
    };

    STAGE(0, 0);
    int cur = 0;
    for (int k0 = 0; k0 < K; k0 += 32) {
        __syncthreads();                        // buf[cur] staged; prev reads done
        if (k0 + 32 < K) STAGE(cur ^ 1, k0 + 32);

        short* smAhi = sm + cur * BUFSH;
        short* smAlo = smAhi + 128 * 32;
        short* smBhi = smAhi + 256 * 32;
        short* smBlo = smAhi + (256 + BN) * 32;

        half8v ahi[4], alo[4], bhi[NW], blo[NW];
#pragma unroll
        for (int i = 0; i < 4; ++i) {
            int ra = wm * 64 + i * 16 + lm;
            int offa = ra * 32 + (lk ^ ((ra >> 1) & 3)) * 8;
            ahi[i] = *(const half8v*)&smAhi[offa];
            alo[i] = *(const half8v*)&smAlo[offa];
        }
#pragma unroll
        for (int j = 0; j < NW; ++j) {
            int rb = wn * (16 * NW) + j * 16 + lm;
            int offb = rb * 32 + (lk ^ ((rb >> 1) & 3)) * 8;
            bhi[j] = *(const half8v*)&smBhi[offb];
            blo[j] = *(const half8v*)&smBlo[offb];
        }
#pragma unroll
        for (int i = 0; i < 4; ++i)
#pragma unroll
            for (int j = 0; j < NW; ++j) {
                acc[i][j]  = __builtin_amdgcn_mfma_f32_16x16x32_f16(ahi[i], bhi[j], acc[i][j], 0, 0, 0);
                acc2[i][j] = __builtin_amdgcn_mfma_f32_16x16x32_f16(ahi[i], blo[j], acc2[i][j], 0, 0, 0);
                acc2[i][j] = __builtin_amdgcn_mfma_f32_16x16x32_f16(alo[i], bhi[j], acc2[i][j], 0, 0, 0);
            }
        cur ^= 1;
    }

    const float ls = 1.0f / 4096.0f;
    __syncthreads();                            // all tile reads complete (LDS reuse)
    // LDS-transpose epilogue -> coalesced float4 stores
    constexpr int SW = 16 * NW + 4;
    float* tile = reinterpret_cast<float*>(sm) + wv * 16 * SW;
    constexpr int LPR = 4 * NW;
    const int rl = lane / LPR, cc = lane % LPR;
#pragma unroll
    for (int i = 0; i < 4; ++i) {
#pragma unroll
        for (int j = 0; j < NW; ++j)
#pragma unroll
            for (int r = 0; r < 4; ++r)
                tile[(lk * 4 + r) * SW + j * 16 + lm] = acc[i][j][r] + ls * acc2[i][j][r] + bb[j];
        constexpr int RPS = 64 / LPR;
#pragma unroll
        for (int s = 0; s < 16 / RPS; ++s) {
            int row = s * RPS + rl;
            float4 v = *(float4*)&tile[row * SW + cc * 4];
            *(float4*)(out + (size_t)(m0 + wm * 64 + i * 16 + row) * N +
                       n0 + wn * (16 * NW) + cc * 4) = v;
        }
    }
}

// ---------------- gates GEMM + fused LSTM cell: 2 waves, 64x128 per wave --------------
// Block 128x128, BK=32, dbuf LDS (64KB). Wave wv owns rows wv*64..+64, all 128 cols.
// acc[i][j]: i = M-frag (4), j = N-frag (8). Per-CU ds_read volume drops 25% vs 4-wave.
__global__ __launch_bounds__(128) void gemm_big(
    const short* __restrict__ Ahi, const short* __restrict__ Alo, int lda,
    const short* __restrict__ Whi, const short* __restrict__ Wlo,
    const float* __restrict__ bias,
    float* __restrict__ Cst, short* __restrict__ Xh, short* __restrict__ Xl,
    int N, int K) {
    constexpr int BUFSH = 512 * 32;                // shorts per buffer (A+B, hi+lo)
    __shared__ short sm[2 * BUFSH];

    // SWZ=1: grid(16,32) -> 8x8 super-tile per XCD
    int bx = blockIdx.x, by = blockIdx.y;
    {
        int w = bx + (by << 4), c = w & 7, k = w >> 3;
        by = ((c >> 1) << 3) | (k >> 3);
        bx = ((c & 1) << 3) | (k & 7);
    }

    const int tid = threadIdx.x;                   // 128 threads
    const int lane = tid & 63;
    const int wv = tid >> 6;                       // 0/1
    const int lm = lane & 15, lk = lane >> 4;
    const int m0 = by * 128, n0 = bx * 128;

    f32x4 acc[4][8] = {};
    f32x4 acc2[4][8] = {};

    float bb[8];
#pragma unroll
    for (int j = 0; j < 8; ++j) bb[j] = bias[n0 + j * 16 + lm];

    // stage 128x32 A (hi,lo) + 128x32 B (hi,lo): 512 chunks each of 16B, 128 threads
    auto STAGE = [&](int buf, int k0) {
        short* base = sm + buf * BUFSH;
#pragma unroll
        for (int rep = 0; rep < 4; ++rep) {
            int c = rep * 128 + tid;
            int row = c >> 2;
            int qg = (c & 3) ^ ((row >> 1) & 3);
            size_t aoff = (size_t)(m0 + row) * lda + k0 + qg * 8;
            size_t boff = (size_t)(n0 + row) * K + k0 + qg * 8;
            GLOAD16(Ahi + aoff, base + c * 8);
            GLOAD16(Alo + aoff, base + 4096 + c * 8);
            GLOAD16(Whi + boff, base + 8192 + c * 8);
            GLOAD16(Wlo + boff, base + 12288 + c * 8);
        }
    };

    STAGE(0, 0);
    int cur = 0;
    for (int k0 = 0; k0 < K; k0 += 32) {
        __syncthreads();                           // buf[cur] staged; prev reads done
        if (k0 + 32 < K) STAGE(cur ^ 1, k0 + 32);

        short* base = sm + cur * BUFSH;
        half8v ah[4], al[4];
#pragma unroll
        for (int i = 0; i < 4; ++i) {
            int ra = wv * 64 + i * 16 + lm;
            int offa = ra * 32 + (lk ^ ((ra >> 1) & 3)) * 8;
            ah[i] = *(const half8v*)&base[offa];
            al[i] = *(const half8v*)&base[4096 + offa];
        }
#pragma unroll
        for (int j = 0; j < 8; ++j) {
            int rb = j * 16 + lm;
            int offb = rb * 32 + (lk ^ ((rb >> 1) & 3)) * 8;
            half8v bh = *(const half8v*)&base[8192 + offb];
            half8v bl = *(const half8v*)&base[12288 + offb];
#pragma unroll
            for (int i = 0; i < 4; ++i) {
                acc[i][j]  = __builtin_amdgcn_mfma_f32_16x16x32_f16(ah[i], bh, acc[i][j], 0, 0, 0);
                acc2[i][j] = __builtin_amdgcn_mfma_f32_16x16x32_f16(ah[i], bl, acc2[i][j], 0, 0, 0);
                acc2[i][j] = __builtin_amdgcn_mfma_f32_16x16x32_f16(al[i], bh, acc2[i][j], 0, 0, 0);
            }
        }
        cur ^= 1;
    }

    // fused LSTM cell epilogue. col = n0 + j*16 + lm, j = jj*4 + gate;
    // gate = j&3, h = lm + 16*((n0>>6) + jj)
    const float ls = 1.0f / 4096.0f;
#pragma unroll
    for (int jj = 0; jj < 2; ++jj) {
        const int h = lm + 16 * ((n0 >> 6) + jj);
#pragma unroll
        for (int i = 0; i < 4; ++i) {
#pragma unroll
            for (int r = 0; r < 4; ++r) {
                int brow = m0 + wv * 64 + i * 16 + lk * 4 + r;
                float gi = acc[i][jj * 4 + 0][r] + ls * acc2[i][jj * 4 + 0][r] + bb[jj * 4 + 0];
                float gf = acc[i][jj * 4 + 1][r] + ls * acc2[i][jj * 4 + 1][r] + bb[jj * 4 + 1];
                float gg = acc[i][jj * 4 + 2][r] + ls * acc2[i][jj * 4 + 2][r] + bb[jj * 4 + 2];
                float go = acc[i][jj * 4 + 3][r] + ls * acc2[i][jj * 4 + 3][r] + bb[jj * 4 + 3];
                size_t ch = ((size_t)brow << 9) + h;
                float c = sigm(gf) * Cst[ch] + sigm(gi) * tanhf(gg);
                float hn = sigm(go) * tanhf(c);
                Cst[ch] = c;
                short shi, slo; split2(hn, shi, slo);
                size_t xb = ((size_t)brow << 10) + 512 + h;
                Xh[xb] = shi; Xl[xb] = slo;
            }
        }
    }
}

// ---------------- attention + argmax + mask + gather into X_next ----------------
__global__ __launch_bounds__(256) void k_attn(const float* __restrict__ W1E,
                                              const float* __restrict__ W2h,
                                              const float* __restrict__ vw,
                                              const float* __restrict__ vbp,
                                              const float* __restrict__ inps,
                                              short* __restrict__ Xhi,
                                              short* __restrict__ Xlo,
                                              int* __restrict__ mask,
                                              float* __restrict__ probs,
                                              float* __restrict__ ptrs,
                                              int step) {
    const int b = blockIdx.x;
    const int tid = threadIdx.x;
    const int lane = tid & 63;
    const int wv = tid >> 6;
    __shared__ float sU[Tn];
    __shared__ int sptr;

    const float4* w2p = (const float4*)(W2h + (size_t)b * Hn + lane * 8);
    float4 w2a = w2p[0], w2b = w2p[1];
    const float4* vp = (const float4*)(vw + lane * 8);
    float4 va = vp[0], vb4 = vp[1];
    float vbias = vbp[0];

#pragma unroll
    for (int q = 0; q < 2; ++q) {
        int t = wv * 2 + q;
        const float4* w1 = (const float4*)(W1E + ((size_t)b << 12) + t * Hn + lane * 8);
        float4 u0 = w1[0], u1 = w1[1];
        float p = va.x * tanhf(u0.x + w2a.x) + va.y * tanhf(u0.y + w2a.y)
                + va.z * tanhf(u0.z + w2a.z) + va.w * tanhf(u0.w + w2a.w)
                + vb4.x * tanhf(u1.x + w2b.x) + vb4.y * tanhf(u1.y + w2b.y)
                + vb4.z * tanhf(u1.z + w2b.z) + vb4.w * tanhf(u1.w + w2b.w);
#pragma unroll
        for (int off = 32; off; off >>= 1) p += __shfl_down(p, off, 64);
        if (lane == 0) sU[t] = p + vbias;
    }
    __syncthreads();

    if (tid == 0) {
        int mk = mask[b];
        float best = -1e30f;
        int ptr = 0;
#pragma unroll
        for (int t = 0; t < Tn; ++t) {
            probs[(size_t)b * 64 + step * 8 + t] = sU[t];
            if (!((mk >> t) & 1) && sU[t] > best) { best = sU[t]; ptr = t; }
        }
        mask[b] = mk | (1 << ptr);
        ptrs[(size_t)b * 8 + step] = (float)ptr;
        sptr = ptr;
    }
    __syncthreads();
    const float2* src = (const float2*)(inps + ((size_t)b << 12) + (size_t)sptr * Hn);
    float2 v = src[tid];
    short h0, l0, h1, l1;
    split2(v.x, h0, l0); split2(v.y, h1, l1);
    size_t xb = ((size_t)b << 10) + tid * 2;
    *(short2*)&Xhi[xb] = make_short2(h0, h1);
    *(short2*)&Xlo[xb] = make_short2(l0, l1);
}

// ---------------- launch ----------------
extern "C" void kernel_launch(void* const* d_in, const int* in_sizes, int n_in,
                              void* d_out, int out_size, void* d_ws, size_t ws_size,
                              hipStream_t stream) {
    const float* inps  = (const float*)d_in[0];
    const float* enc   = (const float*)d_in[1];
    const float* convw = (const float*)d_in[2];
    const float* convb = (const float*)d_in[3];
    const float* Wih   = (const float*)d_in[4];
    const float* Whh   = (const float*)d_in[5];
    const float* bih   = (const float*)d_in[6];
    const float* bhh   = (const float*)d_in[7];
    const float* W1    = (const float*)d_in[8];
    const float* b1    = (const float*)d_in[9];
    const float* W2    = (const float*)d_in[10];
    const float* b2    = (const float*)d_in[11];
    const float* vw    = (const float*)d_in[12];
    const float* vb    = (const float*)d_in[13];

    float* out   = (float*)d_out;
    float* probs = out;                       // [B, 8, 8]
    float* ptrs  = out + (size_t)Bn * 64;     // [B, 8] as float

    char* wsb = (char*)d_ws;
    float* W1E    = (float*)wsb;                          // [0,64MB) fp32 [B*T,512]
    short* encHi  = (short*)(wsb + (64ull << 20));        // dead after W1E gemm
    short* encLo  = (short*)(wsb + (96ull << 20));        // dead after W1E gemm
    short* Xhi1   = (short*)(wsb + (64ull << 20));        // 8MB fp16 [B,1024]
    short* Xlo1   = (short*)(wsb + (72ull << 20));        // 8MB
    float* W2h    = (float*)(wsb + (96ull << 20));        // 8MB fp32 [B,512]
    float* C      = (float*)(wsb + (104ull << 20));       // 8MB fp32 [B,512]
    short* Xhi0   = (short*)(wsb + (112ull << 20));       // 8MB
    short* Xlo0   = (short*)(wsb + (120ull << 20));       // 8MB
    short* WcatHi = (short*)(wsb + (128ull << 20));       // 4MB [2048,1024]
    short* WcatLo = (short*)(wsb + (132ull << 20));       // 4MB
    short* W1hi   = (short*)(wsb + (136ull << 20));
    short* W1lo   = (short*)(wsb + (136ull << 20) + (512u << 10));
    short* W2hi   = (short*)(wsb + (137ull << 20));
    short* W2lo   = (short*)(wsb + (137ull << 20) + (512u << 10));
    float* bcat   = (float*)(wsb + (138ull << 20));
    int*   mask   = (int*)(wsb + (138ull << 20) + (16u << 10));

    k_prep<<<(2048 * 1024) / 256, 256, 0, stream>>>(Wih, Whh, bih, bhh, WcatHi, WcatLo, bcat);
    k_split4<<<(Bn * Tn * Hn / 4) / 256, 256, 0, stream>>>(enc, encHi, encLo, Bn * Tn * Hn / 4);
    k_split4<<<(Hn * Hn / 4) / 256, 256, 0, stream>>>(W1, W1hi, W1lo, Hn * Hn / 4);
    k_split4<<<(Hn * Hn / 4) / 256, 256, 0, stream>>>(W2, W2hi, W2lo, Hn * Hn / 4);

    // W1E = enc @ W1^T + b1   [B*T, 512], K=512
    gemm_t<4, 2><<<dim3(Hn / 128, (Bn * Tn) / 128), 256, 0, stream>>>(
        encHi, encLo, Hn, W1hi, W1lo, b1, W1E, Hn, Hn);

    k_init<<<(Bn * Hn) / 256, 256, 0, stream>>>(enc, convw, convb, Xhi0, Xlo0, C, mask);

    for (int step = 0; step < Tn; ++step) {
        short* Xh_cur = (step & 1) ? Xhi1 : Xhi0;
        short* Xl_cur = (step & 1) ? Xlo1 : Xlo0;
        short* Xh_nxt = (step & 1) ? Xhi0 : Xhi1;
        short* Xl_nxt = (step & 1) ? Xlo0 : Xlo1;

        // gates GEMM + fused LSTM cell (2-wave, 64x128/wave)
        gemm_big<<<dim3(2048 / 128, Bn / 128), 128, 0, stream>>>(
            Xh_cur, Xl_cur, 1024, WcatHi, WcatLo, bcat, C, Xh_nxt, Xl_nxt, 2048, 1024);
        // W2h = h @ W2^T + b2   [4096,512], K=512  (h = X_next[:,512:])
        gemm_t<2, 3><<<dim3(Hn / 64, Bn / 128), 256, 0, stream>>>(
            Xh_nxt + 512, Xl_nxt + 512, 1024, W2hi, W2lo, b2, W2h, Hn, Hn);
        // attention, argmax, mask, gather next input into X_next[:,0:512]
        k_attn<<<Bn, 256, 0, stream>>>(W1E, W2h, vw, vb, inps, Xh_nxt, Xl_nxt, mask, probs, ptrs, step);
    }
}